// Round 19
// baseline (324.025 us; speedup 1.0000x reference)
//
#include <hip/hip_runtime.h>
#include <cstddef>

typedef unsigned short ushort_t;
typedef __attribute__((ext_vector_type(8))) short bf16x8;
typedef __attribute__((ext_vector_type(4))) float f32x4;
typedef __attribute__((ext_vector_type(16))) float f32x16;

// ---------------- workspace layout (float offsets) ----------------
#define WS_P0     0u         /* p0 f32 4096x256 = 1048576 f; dots later */
#define WS_DOTS   0u
#define WS_OBK    524288u    /* obk written only after p0/dots are dead */
#define WS_HN0    1048576u   /* 4096x256 f32 */
#define WS_H1     2097152u   /* 4096x128 */
#define WS_H1N    2621440u   /* 4096x128 */
#define WS_P1     3145728u   /* p1 f32 4096x128; pvb later */
#define WS_PVB    3145728u
#define WS_HN1    3670016u   /* 4096x128 */
#define WS_H2     4194304u   /* 4096x128 */
#define WS_X      4718592u   /* synth 2048x128 */
// ---- contiguous zero region (one memset): ----
#define WS_BITMAP 5767168u   /* 524288 words */
#define WS_NEIGH  6291456u   /* 786432 */
#define WS_ROWSUM 7077888u   /* 6144 */
#define WS_SCAL   7084032u   /* 16 floats: [S_all, s1, -, sub, ecount_f] */
#define WS_DEG    7084048u   /* int 4096 */
// ---- end zero region ----
#define WS_NN     7088144u   /* int 1024 */
#define WS_CUR    7089168u   /* int 4096 */
#define WS_ROWPTR 7093264u   /* int 4097 */
#define WS_EIDX   7097361u   /* int 69632 */

__device__ inline ushort_t f2bf(float f) {
  unsigned u = __float_as_uint(f);
  u += 0x7fff + ((u >> 16) & 1);   // round-to-nearest-even
  return (ushort_t)(u >> 16);
}
__device__ inline float bf2f(ushort_t h) {
  return __uint_as_float((unsigned)h << 16);
}

// ---------------- mgemm: NT GEMM on matrix cores via split-bf16 -----------
// C ≈ Ah·Bh + Al·Bh + Ah·Bl (rel err ~2^-16). 64x64 tile, 4 waves x 32x32
// MFMA (r15: 32x64 tile = 1.5x operand traffic -> slower; keep 64x64).
// Output modes: C f32 | Cb packed-obk bf16 | logits epilogue (Wclf != null).
__global__ __launch_bounds__(256, 2) void mgemm(
    const float* __restrict__ A, int lda,
    const float* __restrict__ B, int ldb,
    const float* __restrict__ A2, int lda2,
    const float* __restrict__ B2, int ldb2,
    const float* __restrict__ bias,
    float* __restrict__ C, int ldc,
    int K, int relu,
    ushort_t* __restrict__ Cb,
    const float* __restrict__ a2scale,
    const float* __restrict__ Ahi,
    const float* __restrict__ Wclf,
    const float* __restrict__ scal4,
    float* __restrict__ outp)
{
  __shared__ ushort_t AhS[64][36], AlS[64][36], BhS[64][36], BlS[64][36];
  const int tid = threadIdx.x;
  const int lane = tid & 63;
  const int w = tid >> 6;
  const int lo = lane & 31, hi = lane >> 5;
  const int iq = (w & 1) << 5, jq = (w >> 1) << 5;   // wave's 32x32 quadrant
  const int i0 = blockIdx.y << 6, j0 = blockIdx.x << 6;
  const int lr = tid >> 2;           // loader row 0..63
  const int c8 = (tid & 3) << 3;     // loader col 0,8,16,24
  f32x16 acc;
#pragma unroll
  for (int t = 0; t < 16; ++t) acc[t] = 0.f;
  const int npass = (A2 != nullptr) ? 2 : 1;
  for (int pass = 0; pass < npass; ++pass) {
    const float* Ap = pass ? A2 : A; const int la = pass ? lda2 : lda;
    const float* Bp = pass ? B2 : B; const int lb = pass ? ldb2 : ldb;
    const float* Arow = (pass == 0 && Ahi != nullptr && (i0 + lr) >= 4096)
        ? (Ahi + (size_t)(i0 + lr - 4096) * la)
        : (Ap + (size_t)(i0 + lr) * la);
    const float* Brow = Bp + (size_t)(j0 + lr) * lb;
    const float sc = (pass && a2scale) ? __frcp_rn(a2scale[i0 + lr] + 1.f) : 1.f;
    for (int k0 = 0; k0 < K; k0 += 32) {
      float av[8], bv[8];
      {
        const float4 a0 = *(const float4*)(Arow + k0 + c8);
        const float4 a1 = *(const float4*)(Arow + k0 + c8 + 4);
        const float4 b0 = *(const float4*)(Brow + k0 + c8);
        const float4 b1 = *(const float4*)(Brow + k0 + c8 + 4);
        av[0]=a0.x*sc; av[1]=a0.y*sc; av[2]=a0.z*sc; av[3]=a0.w*sc;
        av[4]=a1.x*sc; av[5]=a1.y*sc; av[6]=a1.z*sc; av[7]=a1.w*sc;
        bv[0]=b0.x; bv[1]=b0.y; bv[2]=b0.z; bv[3]=b0.w;
        bv[4]=b1.x; bv[5]=b1.y; bv[6]=b1.z; bv[7]=b1.w;
      }
      __syncthreads();   // all waves done reading LDS of previous step
      {
        ushort_t ah8[8], al8[8], bh8[8], bl8[8];
#pragma unroll
        for (int e = 0; e < 8; ++e) {
          const ushort_t ah = f2bf(av[e]);
          ah8[e] = ah; al8[e] = f2bf(av[e] - bf2f(ah));
          const ushort_t bh = f2bf(bv[e]);
          bh8[e] = bh; bl8[e] = f2bf(bv[e] - bf2f(bh));
        }
        *(bf16x8*)&AhS[lr][c8] = *(bf16x8*)ah8;
        *(bf16x8*)&AlS[lr][c8] = *(bf16x8*)al8;
        *(bf16x8*)&BhS[lr][c8] = *(bf16x8*)bh8;
        *(bf16x8*)&BlS[lr][c8] = *(bf16x8*)bl8;
      }
      __syncthreads();
#pragma unroll
      for (int kk = 0; kk < 32; kk += 16) {
        const bf16x8 ahf = *(const bf16x8*)&AhS[iq + lo][kk + (hi << 3)];
        const bf16x8 alf = *(const bf16x8*)&AlS[iq + lo][kk + (hi << 3)];
        const bf16x8 bhf = *(const bf16x8*)&BhS[jq + lo][kk + (hi << 3)];
        const bf16x8 blf = *(const bf16x8*)&BlS[jq + lo][kk + (hi << 3)];
        acc = __builtin_amdgcn_mfma_f32_32x32x16_bf16(ahf, bhf, acc, 0, 0, 0);
        acc = __builtin_amdgcn_mfma_f32_32x32x16_bf16(alf, bhf, acc, 0, 0, 0);
        acc = __builtin_amdgcn_mfma_f32_32x32x16_bf16(ahf, blf, acc, 0, 0, 0);
      }
    }
  }
  // epilogue: D row=(r&3)+8(r>>2)+4hi (A-side), col=lo (B-side)
  const int col = j0 + jq + lo;
  if (Wclf) {
    // logits mode: per-lane partials, reduce over the 32-lane col group,
    // one atomicAdd per (row, class) per wave. Loss scalar from block (0,0).
    const float w0c = Wclf[col], w1c = Wclf[128 + col];
#pragma unroll
    for (int t = 0; t < 16; ++t) {
      float q0 = acc[t] * w0c, q1 = acc[t] * w1c;
#pragma unroll
      for (int m = 1; m < 32; m <<= 1) {
        q0 += __shfl_xor(q0, m, 64);
        q1 += __shfl_xor(q1, m, 64);
      }
      if (lo == 0) {
        const int row = i0 + iq + (t & 3) + ((t >> 2) << 3) + (hi << 2);
        atomicAdd(&outp[(size_t)row * 2 + 0], q0);
        atomicAdd(&outp[(size_t)row * 2 + 1], q1);
      }
    }
    if (blockIdx.x == 0 && blockIdx.y == 0 && tid == 0) {
      const float cnt = scal4[4];
      const float neg_w = cnt / (16777216.f - cnt);
      outp[18432] = neg_w * (scal4[0] - scal4[3]) + scal4[1];
    }
    return;
  }
  const float badd = bias ? bias[col] : 0.f;
#pragma unroll
  for (int t = 0; t < 16; ++t) {
    float o = acc[t] + badd;
    if (relu) o = fmaxf(o, 0.f);
    const int row = i0 + iq + (t & 3) + ((t >> 2) << 3) + (hi << 2);
    if (Cb) {
      const size_t off = ((size_t)(row >> 5) << 12) +
          (size_t)(((col >> 4) << 9) +
                   (((((col >> 3) & 1) << 5) + (row & 31)) << 3) + (col & 7));
      Cb[off] = f2bf(o);
    } else {
      C[(size_t)row * ldc + col] = o;
    }
  }
}

// ---------------- CSR build (multi-block; r10 lesson: no single-block) -----
__global__ void count_bitmap_k(const int* __restrict__ src, const int* __restrict__ dst,
                               int* __restrict__ deg, unsigned* __restrict__ bitmap, int E) {
  const int e = blockIdx.x * 256 + threadIdx.x;
  if (e < E) {
    const int d_ = dst[e], s_ = src[e];
    atomicAdd(&deg[d_], 1);
    const unsigned cell = ((unsigned)d_ << 12) + (unsigned)s_;
    atomicOr(&bitmap[cell >> 5], 1u << (cell & 31));
  }
}

__global__ __launch_bounds__(1024) void scan_k(const int* __restrict__ deg,
                                               int* __restrict__ rowptr,
                                               int* __restrict__ cursor) {
  __shared__ int sums[1024];
  const int t = threadIdx.x;
  const int4 d = *(const int4*)(deg + (t << 2));
  const int local = d.x + d.y + d.z + d.w;
  sums[t] = local;
  __syncthreads();
  for (int off = 1; off < 1024; off <<= 1) {
    int v = (t >= off) ? sums[t - off] : 0;
    __syncthreads();
    sums[t] += v;
    __syncthreads();
  }
  const int excl = sums[t] - local;
  const int o0 = excl, o1 = o0 + d.x, o2 = o1 + d.y, o3 = o2 + d.z;
  rowptr[(t<<2)+0]=o0; rowptr[(t<<2)+1]=o1; rowptr[(t<<2)+2]=o2; rowptr[(t<<2)+3]=o3;
  cursor[(t<<2)+0]=o0; cursor[(t<<2)+1]=o1; cursor[(t<<2)+2]=o2; cursor[(t<<2)+3]=o3;
  if (t == 1023) rowptr[4096] = sums[1023];
}

__global__ void fill_k(const int* __restrict__ src, const int* __restrict__ dst,
                       int* __restrict__ cursor, int* __restrict__ eidx, int E) {
  const int e = blockIdx.x * 256 + threadIdx.x;
  if (e < E) {
    const int p = atomicAdd(&cursor[dst[e]], 1);
    eidx[p] = src[e];
  }
}

// segment_max as CSR gather (f32 p). Dual accumulators keep 2 row-gathers
// in flight (exact: max associative; p >= 0 and non-empty segments).
__global__ void segmax_k(const float* __restrict__ p, const int* __restrict__ rowptr,
                         const int* __restrict__ eidx, float* __restrict__ hn, int F) {
  const int row = blockIdx.x, f = threadIdx.x;  // blockDim == F
  const int b = rowptr[row], e = rowptr[row + 1];
  float m0 = 0.f, m1 = 0.f;
  int k = b;
  for (; k + 1 < e; k += 2) {
    m0 = fmaxf(m0, p[(size_t)eidx[k] * F + f]);
    m1 = fmaxf(m1, p[(size_t)eidx[k + 1] * F + f]);
  }
  if (k < e) m0 = fmaxf(m0, p[(size_t)eidx[k] * F + f]);
  hn[(size_t)row * F + f] = fmaxf(m0, m1);
}

// ---------------- small fused elementwise / reductions ----------------
__device__ inline float wave_sum(float v) {
#pragma unroll
  for (int o = 32; o > 0; o >>= 1) v += __shfl_down(v, o, 64);
  return v;
}

__global__ void relu_l2norm_k(const float* __restrict__ in, float* __restrict__ out) {
  const int row = blockIdx.x, f = threadIdx.x;  // 128 threads
  const float v = fmaxf(in[(size_t)row * 128 + f], 0.f);
  const float ss = wave_sum(v * v);
  __shared__ float w[2];
  if ((f & 63) == 0) w[f >> 6] = ss;
  __syncthreads();
  const float denom = fmaxf(sqrtf(w[0] + w[1]), 1e-12f);
  out[(size_t)row * 128 + f] = v / denom;
}

// nearest neighbor (excluding self); sqn comes from the diag of dots
__global__ void argmin_k(const float* __restrict__ dots, int* __restrict__ nn) {
  __shared__ float sqd[1024];
  const int i = blockIdx.x, tid = threadIdx.x;  // 256 threads
#pragma unroll
  for (int z = 0; z < 4; ++z) {
    const int j = (tid << 2) + z;
    sqd[j] = dots[(size_t)j * 1025];   // dots[j][j]
  }
  __syncthreads();
  float best = 3.402823466e38f; int bidx = 0x7fffffff;
  const float si = sqd[i];
  for (int j = tid; j < 1024; j += 256) {
    if (j == i) continue;
    float d2 = si + sqd[j] - 2.f * dots[(size_t)i * 1024 + j];
    d2 = fmaxf(d2, 0.f);
    if (d2 < best || (d2 == best && j < bidx)) { best = d2; bidx = j; }
  }
  __shared__ float bv[256]; __shared__ int bi[256];
  bv[tid] = best; bi[tid] = bidx;
  __syncthreads();
  for (int s = 128; s > 0; s >>= 1) {
    if (tid < s) {
      if (bv[tid+s] < bv[tid] || (bv[tid+s] == bv[tid] && bi[tid+s] < bi[tid])) {
        bv[tid] = bv[tid+s]; bi[tid] = bi[tid+s];
      }
    }
    __syncthreads();
  }
  if (tid == 0) nn[i] = bi[0];
}

// build synth rows (SMOTE interp) + pack pvb + pre-write y & logits bias.
__global__ __launch_bounds__(256) void build_pack_k(
    const float* __restrict__ h2, const int* __restrict__ nn,
    const float* __restrict__ gaps, float* __restrict__ synth,
    ushort_t* __restrict__ pvb,
    const int* __restrict__ labels, const float* __restrict__ bclf,
    float* __restrict__ outp) {
  __shared__ ushort_t s[4096];  // [32 j][128 f] bf16
  const int jt = blockIdx.x, tid = threadIdx.x;
  if (tid < 32) {
    const int i = (jt << 5) + tid;
    outp[(size_t)i * 2 + 0] = bclf[0];
    outp[(size_t)i * 2 + 1] = bclf[1];
    outp[12288 + i] = (i < 4096) ? (float)labels[i] : 1.f;
  }
  if (jt < 128) {
    const float* ip = h2 + ((size_t)jt << 12);
#pragma unroll
    for (int k = 0; k < 4; ++k) {
      const float4 v = *(const float4*)(ip + (tid << 4) + (k << 2));
      ushort4 h; h.x = f2bf(v.x); h.y = f2bf(v.y); h.z = f2bf(v.z); h.w = f2bf(v.w);
      *(ushort4*)(s + (tid << 4) + (k << 2)) = h;
    }
  } else {
    const int row = tid >> 3;                       // 0..31
    const int sIdx = ((jt - 128) << 5) + row;       // synth row (= 2i+rep)
    const int i = sIdx >> 1;
    const float g = gaps[sIdx];
    const int ni = nn[i];
#pragma unroll
    for (int k = 0; k < 4; ++k) {
      const int f = ((tid & 7) << 4) + (k << 2);
      const float4 c4 = *(const float4*)(h2 + (size_t)i * 128 + f);
      const float4 n4 = *(const float4*)(h2 + (size_t)ni * 128 + f);
      float4 v;
      v.x = c4.x + g * (n4.x - c4.x);
      v.y = c4.y + g * (n4.y - c4.y);
      v.z = c4.z + g * (n4.z - c4.z);
      v.w = c4.w + g * (n4.w - c4.w);
      *(float4*)(synth + (size_t)sIdx * 128 + f) = v;
      ushort4 h; h.x = f2bf(v.x); h.y = f2bf(v.y); h.z = f2bf(v.z); h.w = f2bf(v.w);
      *(ushort4*)(s + (row << 7) + f) = h;
    }
  }
  __syncthreads();
  const int u = tid & 31, ft = (tid >> 5) & 3, cc = tid >> 7;
  ushort_t* op = pvb + ((size_t)jt << 12) + (cc << 11) + (ft << 9);
#pragma unroll
  for (int m = 0; m < 2; ++m) {
    const int l = (u << 1) + m;
    const int f = (ft << 5) + (l & 31);
    const int jb = (cc << 4) + ((l >> 5) << 3);
    ushort4 o0, o1;
    o0.x = s[(jb + 0) * 128 + f]; o0.y = s[(jb + 1) * 128 + f];
    o0.z = s[(jb + 2) * 128 + f]; o0.w = s[(jb + 3) * 128 + f];
    o1.x = s[(jb + 4) * 128 + f]; o1.y = s[(jb + 5) * 128 + f];
    o1.z = s[(jb + 6) * 128 + f]; o1.w = s[(jb + 7) * 128 + f];
    *(ushort4*)(op + (l << 3) + 0) = o0;
    *(ushort4*)(op + (l << 3) + 4) = o1;
  }
}

// ---------------- fused MFMA v12: 3 blocks/CU uniform occupancy ----------
// r17 insight: grid size (not the 2/CU cap) binds occupancy — 384 blocks on
// 256 CUs is 1-2 blocks/CU IMBALANCED; the 4-wave CUs are the critical path.
// v12: grid (48,16) = 768 = exactly 3/CU uniform, enabled by slimming the
// per-wave state under the 170-reg 3-wave budget (r6 lesson: exceeding it
// spills catastrophically): single 8-deep S chain (-16), chunked sigmoid
// p8 (-8), per-chunk bvf (-16 peak), no a-prefetch (a dead during PV).
__global__ __launch_bounds__(256, 3) void fused_mfma(
    const ushort_t* __restrict__ obk,  // packed A/Q frags [192][8][64][8]
    const ushort_t* __restrict__ pvb,  // packed PV B frags [192][2][4][64][8]
    const unsigned* __restrict__ bitmap,
    float* __restrict__ neigh,         // 6144x128, pre-zeroed
    float* __restrict__ rowsum,        // 6144, pre-zeroed
    float* __restrict__ scal)          // [S_all, s1, -, sub, ecnt], pre-zeroed
{
  __shared__ float wred[4][4];
  const int tid = threadIdx.x;
  const int w = tid >> 6;
  const int lane = tid & 63;
  const int lo = lane & 31, hi = lane >> 5;
  const int it = (blockIdx.x << 2) + w;  // wave's i-tile (32 rows)
  const int iw = it << 5;
  const int jt0 = blockIdx.y * 12;       // shared j-strip: 12 tiles
  const bool loss_i = (it < 128);        // i < 4096 (wave-uniform)

  bf16x8 qf[8];
  {
    const ushort_t* qp = obk + ((size_t)it << 12) + (lane << 3);
#pragma unroll
    for (int c = 0; c < 8; ++c) qf[c] = *(const bf16x8*)(qp + (c << 9));
  }
  f32x16 oacc[4];
#pragma unroll
  for (int ft = 0; ft < 4; ++ft)
#pragma unroll
    for (int r = 0; r < 16; ++r) oacc[ft][r] = 0.f;
  float rs = 0.f, s_all = 0.f, s1a = 0.f, suba = 0.f, ecf = 0.f;

  for (int t = 0; t < 12; ++t) {
    const int jt = jt0 + t;
    // K-frags for this tile (no prefetch: keeps 'a' dead during PV -> fits
    // the 3-wave register budget; exposed latency covered by 12 waves/CU)
    bf16x8 a[8];
    {
      const ushort_t* kp = obk + ((size_t)jt << 12) + (lane << 3);
#pragma unroll
      for (int c = 0; c < 8; ++c) a[c] = *(const bf16x8*)(kp + (c << 9));
    }
    const bool loss_t = loss_i && (jt < 128);
    unsigned word = 0u;
    if (loss_t) word = bitmap[((unsigned)(iw + lo) << 7) + (unsigned)jt];
    // S^T: single 8-deep chain (16 accumulator regs)
    f32x16 s;
#pragma unroll
    for (int r = 0; r < 16; ++r) s[r] = 0.f;
    __builtin_amdgcn_s_setprio(1);
#pragma unroll
    for (int c = 0; c < 8; ++c)
      s = __builtin_amdgcn_mfma_f32_32x32x16_bf16(a[c], qf[c], s, 0, 0, 0);
    __builtin_amdgcn_s_setprio(0);
    if (loss_t) ecf += (float)__popc(word & (0x0F0F0F0Fu << (hi << 2)));
    // two j-half chunks: sigmoid(8) -> pack -> PV, bvf loaded per chunk
#pragma unroll
    for (int cc = 0; cc < 2; ++cc) {
      bf16x8 bvf[4];
      {
        const ushort_t* vp = pvb + ((size_t)jt << 12) + (cc << 11) + (lane << 3);
#pragma unroll
        for (int ft = 0; ft < 4; ++ft)
          bvf[ft] = *(const bf16x8*)(vp + (ft << 9));
      }
      float p8[8];
      if (loss_t) {
#pragma unroll
        for (int rr = 0; rr < 8; ++rr) {
          const int r = (cc << 3) + rr;
          const float v = s[r];
          const float sg = __builtin_amdgcn_rcpf(1.f + __expf(-v));
          const int jl = (r & 3) + ((r >> 2) << 3) + (hi << 2);
          const float e_ = (float)((word >> jl) & 1u);
          s_all += sg * sg;
          s1a  += e_ * (sg - 1.f) * (sg - 1.f);
          suba += e_ * sg * sg;
          const float tv = (v >= 0.f) ? sg : 0.f;   // sg>=0.5 <=> v>=0
          p8[rr] = tv; rs += tv;
        }
      } else {
#pragma unroll
        for (int rr = 0; rr < 8; ++rr) {
          const float v = s[(cc << 3) + rr];
          const float sg = __builtin_amdgcn_rcpf(1.f + __expf(-v));
          const float tv = (v >= 0.f) ? sg : 0.f;
          p8[rr] = tv; rs += tv;
        }
      }
      unsigned c01, c23, c45, c67;
      asm("v_cvt_pk_bf16_f32 %0, %1, %2" : "=v"(c01) : "v"(p8[0]), "v"(p8[1]));
      asm("v_cvt_pk_bf16_f32 %0, %1, %2" : "=v"(c23) : "v"(p8[2]), "v"(p8[3]));
      asm("v_cvt_pk_bf16_f32 %0, %1, %2" : "=v"(c45) : "v"(p8[4]), "v"(p8[5]));
      asm("v_cvt_pk_bf16_f32 %0, %1, %2" : "=v"(c67) : "v"(p8[6]), "v"(p8[7]));
      const auto w0 = __builtin_amdgcn_permlane32_swap((int)c01, (int)c45, false, false);
      const auto w1 = __builtin_amdgcn_permlane32_swap((int)c23, (int)c67, false, false);
      union { int i[4]; bf16x8 h; } u;
      u.i[0] = w0[0]; u.i[1] = w1[0]; u.i[2] = w0[1]; u.i[3] = w1[1];
      __builtin_amdgcn_s_setprio(1);
#pragma unroll
      for (int ft = 0; ft < 4; ++ft)
        oacc[ft] = __builtin_amdgcn_mfma_f32_32x32x16_bf16(u.h, bvf[ft], oacc[ft], 0, 0, 0);
      __builtin_amdgcn_s_setprio(0);
    }
  }
#pragma unroll
  for (int ft = 0; ft < 4; ++ft)
#pragma unroll
    for (int r = 0; r < 16; ++r) {
      const int ir = (r & 3) + ((r >> 2) << 3) + (hi << 2);
      atomicAdd(&neigh[(size_t)(iw + ir) * 128 + (ft << 5) + lo], oacc[ft][r]);
    }
  rs += __shfl_xor(rs, 32, 64);
  if (hi == 0) atomicAdd(&rowsum[iw + lo], rs);
  {
    float v0 = wave_sum(s_all), v1 = wave_sum(s1a), v2 = wave_sum(suba), v3 = wave_sum(ecf);
    if (lane == 0) { wred[w][0] = v0; wred[w][1] = v1; wred[w][2] = v2; wred[w][3] = v3; }
  }
  __syncthreads();
  if (tid < 4) {
    const float t = wred[0][tid] + wred[1][tid] + wred[2][tid] + wred[3][tid];
    const int dst = (tid == 0) ? 0 : (tid == 1) ? 1 : (tid == 2) ? 3 : 4;
    atomicAdd(&scal[dst], t);
  }
}

// ---------------- launcher ----------------
extern "C" void kernel_launch(void* const* d_in, const int* in_sizes, int n_in,
                              void* d_out, int out_size, void* d_ws, size_t ws_size,
                              hipStream_t stream) {
  const float* feat     = (const float*)d_in[0];
  const int*   src      = (const int*)d_in[2];
  const int*   dst      = (const int*)d_in[3];
  const int*   labels   = (const int*)d_in[4];
  const float* W_pool0  = (const float*)d_in[5];
  const float* b_pool0  = (const float*)d_in[6];
  const float* W_self0  = (const float*)d_in[7];
  const float* W_neigh0 = (const float*)d_in[8];
  const float* b0       = (const float*)d_in[9];
  const float* W_pool1  = (const float*)d_in[10];
  const float* b_pool1  = (const float*)d_in[11];
  const float* W_self1  = (const float*)d_in[12];
  const float* W_neigh1 = (const float*)d_in[13];
  const float* b1       = (const float*)d_in[14];
  const float* de_w     = (const float*)d_in[15];
  const float* W_conv   = (const float*)d_in[16];
  const float* W_clf    = (const float*)d_in[17];
  const float* b_clf    = (const float*)d_in[18];
  const float* gaps     = (const float*)d_in[19];
  const int E = in_sizes[2];  // 69632 (E + self-loops)

  float* ws = (float*)d_ws;
  float* p0       = ws + WS_P0;
  float* dots     = ws + WS_DOTS;
  ushort_t* obk   = (ushort_t*)(ws + WS_OBK);
  float* hn0      = ws + WS_HN0;
  unsigned* bitmap= (unsigned*)(ws + WS_BITMAP);
  float* h1       = ws + WS_H1;
  float* h1n      = ws + WS_H1N;
  float* p1       = ws + WS_P1;
  ushort_t* pvb   = (ushort_t*)(ws + WS_PVB);
  float* hn1      = ws + WS_HN1;
  float* h2       = ws + WS_H2;
  float* synth    = ws + WS_X;
  float* neigh    = ws + WS_NEIGH;
  float* rowsum   = ws + WS_ROWSUM;
  float* scal     = ws + WS_SCAL;
  int* deg        = (int*)(ws + WS_DEG);
  int* nn         = (int*)(ws + WS_NN);
  int* cursor     = (int*)(ws + WS_CUR);
  int* rowptr     = (int*)(ws + WS_ROWPTR);
  int* eidx       = (int*)(ws + WS_EIDX);

  float* outp = (float*)d_out;
  const dim3 blk(256);

  // one contiguous zero region: bitmap + neigh + rowsum + scal + deg
  hipMemsetAsync(bitmap, 0, (size_t)(WS_DEG + 4096 - WS_BITMAP) * 4, stream);

  // CSR build + adjacency bitmap
  count_bitmap_k<<<(E + 255) / 256, blk, 0, stream>>>(src, dst, deg, bitmap, E);
  scan_k<<<1, 1024, 0, stream>>>(deg, rowptr, cursor);
  fill_k<<<(E + 255) / 256, blk, 0, stream>>>(src, dst, cursor, eidx, E);

  // layer 0
  mgemm<<<dim3(4, 64), blk, 0, stream>>>(feat, 256, W_pool0, 256,
                                         nullptr, 0, nullptr, 0,
                                         b_pool0, p0, 256, 256, 1, nullptr, nullptr, nullptr,
                                         nullptr, nullptr, nullptr);
  segmax_k<<<4096, 256, 0, stream>>>(p0, rowptr, eidx, hn0, 256);
  mgemm<<<dim3(2, 64), blk, 0, stream>>>(feat, 256, W_self0, 256,
                                         hn0, 256, W_neigh0, 256,
                                         b0, h1, 128, 256, 0, nullptr, nullptr, nullptr,
                                         nullptr, nullptr, nullptr);
  relu_l2norm_k<<<4096, 128, 0, stream>>>(h1, h1n);

  // layer 1
  mgemm<<<dim3(2, 64), blk, 0, stream>>>(h1n, 128, W_pool1, 128,
                                         nullptr, 0, nullptr, 0,
                                         b_pool1, p1, 128, 128, 1, nullptr, nullptr, nullptr,
                                         nullptr, nullptr, nullptr);
  segmax_k<<<4096, 128, 0, stream>>>(p1, rowptr, eidx, hn1, 128);
  mgemm<<<dim3(2, 64), blk, 0, stream>>>(h1n, 128, W_self1, 128,
                                         hn1, 128, W_neigh1, 128,
                                         b1, h2, 128, 128, 0, nullptr, nullptr, nullptr,
                                         nullptr, nullptr, nullptr);

  // SMOTE: dots gemm (diag doubles as sqn), argmin, synth+pvb pack (+y/bias)
  mgemm<<<dim3(16, 16), blk, 0, stream>>>(h2, 128, h2, 128,
                                          nullptr, 0, nullptr, 0,
                                          nullptr, dots, 1024, 128, 0, nullptr, nullptr, nullptr,
                                          nullptr, nullptr, nullptr);
  argmin_k<<<1024, 256, 0, stream>>>(dots, nn);
  build_pack_k<<<192, blk, 0, stream>>>(h2, nn, gaps, synth, pvb, labels, b_clf, outp);

  // decoder gemm writes obk-packed bf16 directly (dots dead -> obk region ok)
  mgemm<<<dim3(2, 96), blk, 0, stream>>>(h2, 128, de_w, 128,
                                         nullptr, 0, nullptr, 0,
                                         nullptr, nullptr, 0, 128, 0, obk, nullptr, synth,
                                         nullptr, nullptr, nullptr);
  // dense fused pass: S_all/s1/sub/ecount + thresholded P@x + rowsum
  fused_mfma<<<dim3(48, 16), blk, 0, stream>>>(obk, pvb, bitmap, neigh, rowsum, scal);

  // classifier: hc never materialized — logits epilogue + loss in the gemm
  mgemm<<<dim3(2, 96), blk, 0, stream>>>(h2, 128, W_conv, 256,
                                         neigh, 128, W_conv + 128, 256,
                                         nullptr, nullptr, 128, 128, 0, nullptr, rowsum, synth,
                                         W_clf, scal, outp);

  (void)n_in; (void)out_size; (void)ws_size; (void)in_sizes;
}

// Round 20
// 296.524 us; speedup vs baseline: 1.0927x; 1.0927x over previous
//
#include <hip/hip_runtime.h>
#include <cstddef>

typedef unsigned short ushort_t;
typedef __attribute__((ext_vector_type(8))) short bf16x8;
typedef __attribute__((ext_vector_type(4))) float f32x4;
typedef __attribute__((ext_vector_type(16))) float f32x16;

// ---------------- workspace layout (float offsets) ----------------
#define WS_P0     0u         /* p0 f32 4096x256 = 1048576 f; dots later */
#define WS_DOTS   0u
#define WS_OBK    524288u    /* obk written only after p0/dots are dead */
#define WS_HN0    1048576u   /* 4096x256 f32 */
#define WS_H1     2097152u   /* 4096x128 */
#define WS_H1N    2621440u   /* 4096x128 */
#define WS_P1     3145728u   /* p1 f32 4096x128; pvb later */
#define WS_PVB    3145728u
#define WS_HN1    3670016u   /* 4096x128 */
#define WS_H2     4194304u   /* 4096x128 */
#define WS_X      4718592u   /* synth 2048x128 */
// ---- contiguous zero region (one memset): ----
#define WS_BITMAP 5767168u   /* 524288 words */
#define WS_NEIGH  6291456u   /* 786432 */
#define WS_ROWSUM 7077888u   /* 6144 */
#define WS_SCAL   7084032u   /* 16 floats: [S_all, s1, -, sub, ecount_f] */
#define WS_DEG    7084048u   /* int 4096 */
// ---- end zero region ----
#define WS_NN     7088144u   /* int 1024 */
#define WS_CUR    7089168u   /* int 4096 */
#define WS_ROWPTR 7093264u   /* int 4097 */
#define WS_EIDX   7097361u   /* int 69632 */

__device__ inline ushort_t f2bf(float f) {
  unsigned u = __float_as_uint(f);
  u += 0x7fff + ((u >> 16) & 1);   // round-to-nearest-even
  return (ushort_t)(u >> 16);
}
__device__ inline float bf2f(ushort_t h) {
  return __uint_as_float((unsigned)h << 16);
}

// ---------------- mgemm: NT GEMM on matrix cores via split-bf16 -----------
// C ≈ Ah·Bh + Al·Bh + Ah·Bl (rel err ~2^-16). 64x64 tile, 4 waves x 32x32
// MFMA (r15: 32x64 tile = 1.5x operand traffic -> slower; keep 64x64).
// Output modes: C f32 | Cb packed-obk bf16 | logits epilogue (Wclf != null).
__global__ __launch_bounds__(256, 2) void mgemm(
    const float* __restrict__ A, int lda,
    const float* __restrict__ B, int ldb,
    const float* __restrict__ A2, int lda2,
    const float* __restrict__ B2, int ldb2,
    const float* __restrict__ bias,
    float* __restrict__ C, int ldc,
    int K, int relu,
    ushort_t* __restrict__ Cb,
    const float* __restrict__ a2scale,
    const float* __restrict__ Ahi,
    const float* __restrict__ Wclf,
    const float* __restrict__ scal4,
    float* __restrict__ outp)
{
  __shared__ ushort_t AhS[64][36], AlS[64][36], BhS[64][36], BlS[64][36];
  const int tid = threadIdx.x;
  const int lane = tid & 63;
  const int w = tid >> 6;
  const int lo = lane & 31, hi = lane >> 5;
  const int iq = (w & 1) << 5, jq = (w >> 1) << 5;   // wave's 32x32 quadrant
  const int i0 = blockIdx.y << 6, j0 = blockIdx.x << 6;
  const int lr = tid >> 2;           // loader row 0..63
  const int c8 = (tid & 3) << 3;     // loader col 0,8,16,24
  f32x16 acc;
#pragma unroll
  for (int t = 0; t < 16; ++t) acc[t] = 0.f;
  const int npass = (A2 != nullptr) ? 2 : 1;
  for (int pass = 0; pass < npass; ++pass) {
    const float* Ap = pass ? A2 : A; const int la = pass ? lda2 : lda;
    const float* Bp = pass ? B2 : B; const int lb = pass ? ldb2 : ldb;
    const float* Arow = (pass == 0 && Ahi != nullptr && (i0 + lr) >= 4096)
        ? (Ahi + (size_t)(i0 + lr - 4096) * la)
        : (Ap + (size_t)(i0 + lr) * la);
    const float* Brow = Bp + (size_t)(j0 + lr) * lb;
    const float sc = (pass && a2scale) ? __frcp_rn(a2scale[i0 + lr] + 1.f) : 1.f;
    for (int k0 = 0; k0 < K; k0 += 32) {
      float av[8], bv[8];
      {
        const float4 a0 = *(const float4*)(Arow + k0 + c8);
        const float4 a1 = *(const float4*)(Arow + k0 + c8 + 4);
        const float4 b0 = *(const float4*)(Brow + k0 + c8);
        const float4 b1 = *(const float4*)(Brow + k0 + c8 + 4);
        av[0]=a0.x*sc; av[1]=a0.y*sc; av[2]=a0.z*sc; av[3]=a0.w*sc;
        av[4]=a1.x*sc; av[5]=a1.y*sc; av[6]=a1.z*sc; av[7]=a1.w*sc;
        bv[0]=b0.x; bv[1]=b0.y; bv[2]=b0.z; bv[3]=b0.w;
        bv[4]=b1.x; bv[5]=b1.y; bv[6]=b1.z; bv[7]=b1.w;
      }
      __syncthreads();   // all waves done reading LDS of previous step
      {
        ushort_t ah8[8], al8[8], bh8[8], bl8[8];
#pragma unroll
        for (int e = 0; e < 8; ++e) {
          const ushort_t ah = f2bf(av[e]);
          ah8[e] = ah; al8[e] = f2bf(av[e] - bf2f(ah));
          const ushort_t bh = f2bf(bv[e]);
          bh8[e] = bh; bl8[e] = f2bf(bv[e] - bf2f(bh));
        }
        *(bf16x8*)&AhS[lr][c8] = *(bf16x8*)ah8;
        *(bf16x8*)&AlS[lr][c8] = *(bf16x8*)al8;
        *(bf16x8*)&BhS[lr][c8] = *(bf16x8*)bh8;
        *(bf16x8*)&BlS[lr][c8] = *(bf16x8*)bl8;
      }
      __syncthreads();
#pragma unroll
      for (int kk = 0; kk < 32; kk += 16) {
        const bf16x8 ahf = *(const bf16x8*)&AhS[iq + lo][kk + (hi << 3)];
        const bf16x8 alf = *(const bf16x8*)&AlS[iq + lo][kk + (hi << 3)];
        const bf16x8 bhf = *(const bf16x8*)&BhS[jq + lo][kk + (hi << 3)];
        const bf16x8 blf = *(const bf16x8*)&BlS[jq + lo][kk + (hi << 3)];
        acc = __builtin_amdgcn_mfma_f32_32x32x16_bf16(ahf, bhf, acc, 0, 0, 0);
        acc = __builtin_amdgcn_mfma_f32_32x32x16_bf16(alf, bhf, acc, 0, 0, 0);
        acc = __builtin_amdgcn_mfma_f32_32x32x16_bf16(ahf, blf, acc, 0, 0, 0);
      }
    }
  }
  // epilogue: D row=(r&3)+8(r>>2)+4hi (A-side), col=lo (B-side)
  const int col = j0 + jq + lo;
  if (Wclf) {
    // logits mode: per-lane partials, reduce over the 32-lane col group,
    // one atomicAdd per (row, class) per wave. Loss scalar from block (0,0).
    const float w0c = Wclf[col], w1c = Wclf[128 + col];
#pragma unroll
    for (int t = 0; t < 16; ++t) {
      float q0 = acc[t] * w0c, q1 = acc[t] * w1c;
#pragma unroll
      for (int m = 1; m < 32; m <<= 1) {
        q0 += __shfl_xor(q0, m, 64);
        q1 += __shfl_xor(q1, m, 64);
      }
      if (lo == 0) {
        const int row = i0 + iq + (t & 3) + ((t >> 2) << 3) + (hi << 2);
        atomicAdd(&outp[(size_t)row * 2 + 0], q0);
        atomicAdd(&outp[(size_t)row * 2 + 1], q1);
      }
    }
    if (blockIdx.x == 0 && blockIdx.y == 0 && tid == 0) {
      const float cnt = scal4[4];
      const float neg_w = cnt / (16777216.f - cnt);
      outp[18432] = neg_w * (scal4[0] - scal4[3]) + scal4[1];
    }
    return;
  }
  const float badd = bias ? bias[col] : 0.f;
#pragma unroll
  for (int t = 0; t < 16; ++t) {
    float o = acc[t] + badd;
    if (relu) o = fmaxf(o, 0.f);
    const int row = i0 + iq + (t & 3) + ((t >> 2) << 3) + (hi << 2);
    if (Cb) {
      const size_t off = ((size_t)(row >> 5) << 12) +
          (size_t)(((col >> 4) << 9) +
                   (((((col >> 3) & 1) << 5) + (row & 31)) << 3) + (col & 7));
      Cb[off] = f2bf(o);
    } else {
      C[(size_t)row * ldc + col] = o;
    }
  }
}

// ---------------- CSR build (multi-block; r10 lesson: no single-block) -----
__global__ void count_bitmap_k(const int* __restrict__ src, const int* __restrict__ dst,
                               int* __restrict__ deg, unsigned* __restrict__ bitmap, int E) {
  const int e = blockIdx.x * 256 + threadIdx.x;
  if (e < E) {
    const int d_ = dst[e], s_ = src[e];
    atomicAdd(&deg[d_], 1);
    const unsigned cell = ((unsigned)d_ << 12) + (unsigned)s_;
    atomicOr(&bitmap[cell >> 5], 1u << (cell & 31));
  }
}

__global__ __launch_bounds__(1024) void scan_k(const int* __restrict__ deg,
                                               int* __restrict__ rowptr,
                                               int* __restrict__ cursor) {
  __shared__ int sums[1024];
  const int t = threadIdx.x;
  const int4 d = *(const int4*)(deg + (t << 2));
  const int local = d.x + d.y + d.z + d.w;
  sums[t] = local;
  __syncthreads();
  for (int off = 1; off < 1024; off <<= 1) {
    int v = (t >= off) ? sums[t - off] : 0;
    __syncthreads();
    sums[t] += v;
    __syncthreads();
  }
  const int excl = sums[t] - local;
  const int o0 = excl, o1 = o0 + d.x, o2 = o1 + d.y, o3 = o2 + d.z;
  rowptr[(t<<2)+0]=o0; rowptr[(t<<2)+1]=o1; rowptr[(t<<2)+2]=o2; rowptr[(t<<2)+3]=o3;
  cursor[(t<<2)+0]=o0; cursor[(t<<2)+1]=o1; cursor[(t<<2)+2]=o2; cursor[(t<<2)+3]=o3;
  if (t == 1023) rowptr[4096] = sums[1023];
}

__global__ void fill_k(const int* __restrict__ src, const int* __restrict__ dst,
                       int* __restrict__ cursor, int* __restrict__ eidx, int E) {
  const int e = blockIdx.x * 256 + threadIdx.x;
  if (e < E) {
    const int p = atomicAdd(&cursor[dst[e]], 1);
    eidx[p] = src[e];
  }
}

// segment_max as CSR gather (f32 p). Dual accumulators keep 2 row-gathers
// in flight (exact: max associative; p >= 0 and non-empty segments).
__global__ void segmax_k(const float* __restrict__ p, const int* __restrict__ rowptr,
                         const int* __restrict__ eidx, float* __restrict__ hn, int F) {
  const int row = blockIdx.x, f = threadIdx.x;  // blockDim == F
  const int b = rowptr[row], e = rowptr[row + 1];
  float m0 = 0.f, m1 = 0.f;
  int k = b;
  for (; k + 1 < e; k += 2) {
    m0 = fmaxf(m0, p[(size_t)eidx[k] * F + f]);
    m1 = fmaxf(m1, p[(size_t)eidx[k + 1] * F + f]);
  }
  if (k < e) m0 = fmaxf(m0, p[(size_t)eidx[k] * F + f]);
  hn[(size_t)row * F + f] = fmaxf(m0, m1);
}

// ---------------- small fused elementwise / reductions ----------------
__device__ inline float wave_sum(float v) {
#pragma unroll
  for (int o = 32; o > 0; o >>= 1) v += __shfl_down(v, o, 64);
  return v;
}

__global__ void relu_l2norm_k(const float* __restrict__ in, float* __restrict__ out) {
  const int row = blockIdx.x, f = threadIdx.x;  // 128 threads
  const float v = fmaxf(in[(size_t)row * 128 + f], 0.f);
  const float ss = wave_sum(v * v);
  __shared__ float w[2];
  if ((f & 63) == 0) w[f >> 6] = ss;
  __syncthreads();
  const float denom = fmaxf(sqrtf(w[0] + w[1]), 1e-12f);
  out[(size_t)row * 128 + f] = v / denom;
}

// nearest neighbor (excluding self); sqn comes from the diag of dots
__global__ void argmin_k(const float* __restrict__ dots, int* __restrict__ nn) {
  __shared__ float sqd[1024];
  const int i = blockIdx.x, tid = threadIdx.x;  // 256 threads
#pragma unroll
  for (int z = 0; z < 4; ++z) {
    const int j = (tid << 2) + z;
    sqd[j] = dots[(size_t)j * 1025];   // dots[j][j]
  }
  __syncthreads();
  float best = 3.402823466e38f; int bidx = 0x7fffffff;
  const float si = sqd[i];
  for (int j = tid; j < 1024; j += 256) {
    if (j == i) continue;
    float d2 = si + sqd[j] - 2.f * dots[(size_t)i * 1024 + j];
    d2 = fmaxf(d2, 0.f);
    if (d2 < best || (d2 == best && j < bidx)) { best = d2; bidx = j; }
  }
  __shared__ float bv[256]; __shared__ int bi[256];
  bv[tid] = best; bi[tid] = bidx;
  __syncthreads();
  for (int s = 128; s > 0; s >>= 1) {
    if (tid < s) {
      if (bv[tid+s] < bv[tid] || (bv[tid+s] == bv[tid] && bi[tid+s] < bi[tid])) {
        bv[tid] = bv[tid+s]; bi[tid] = bi[tid+s];
      }
    }
    __syncthreads();
  }
  if (tid == 0) nn[i] = bi[0];
}

// build synth rows (SMOTE interp) + pack pvb + pre-write y & logits bias.
__global__ __launch_bounds__(256) void build_pack_k(
    const float* __restrict__ h2, const int* __restrict__ nn,
    const float* __restrict__ gaps, float* __restrict__ synth,
    ushort_t* __restrict__ pvb,
    const int* __restrict__ labels, const float* __restrict__ bclf,
    float* __restrict__ outp) {
  __shared__ ushort_t s[4096];  // [32 j][128 f] bf16
  const int jt = blockIdx.x, tid = threadIdx.x;
  if (tid < 32) {
    const int i = (jt << 5) + tid;
    outp[(size_t)i * 2 + 0] = bclf[0];
    outp[(size_t)i * 2 + 1] = bclf[1];
    outp[12288 + i] = (i < 4096) ? (float)labels[i] : 1.f;
  }
  if (jt < 128) {
    const float* ip = h2 + ((size_t)jt << 12);
#pragma unroll
    for (int k = 0; k < 4; ++k) {
      const float4 v = *(const float4*)(ip + (tid << 4) + (k << 2));
      ushort4 h; h.x = f2bf(v.x); h.y = f2bf(v.y); h.z = f2bf(v.z); h.w = f2bf(v.w);
      *(ushort4*)(s + (tid << 4) + (k << 2)) = h;
    }
  } else {
    const int row = tid >> 3;                       // 0..31
    const int sIdx = ((jt - 128) << 5) + row;       // synth row (= 2i+rep)
    const int i = sIdx >> 1;
    const float g = gaps[sIdx];
    const int ni = nn[i];
#pragma unroll
    for (int k = 0; k < 4; ++k) {
      const int f = ((tid & 7) << 4) + (k << 2);
      const float4 c4 = *(const float4*)(h2 + (size_t)i * 128 + f);
      const float4 n4 = *(const float4*)(h2 + (size_t)ni * 128 + f);
      float4 v;
      v.x = c4.x + g * (n4.x - c4.x);
      v.y = c4.y + g * (n4.y - c4.y);
      v.z = c4.z + g * (n4.z - c4.z);
      v.w = c4.w + g * (n4.w - c4.w);
      *(float4*)(synth + (size_t)sIdx * 128 + f) = v;
      ushort4 h; h.x = f2bf(v.x); h.y = f2bf(v.y); h.z = f2bf(v.z); h.w = f2bf(v.w);
      *(ushort4*)(s + (row << 7) + f) = h;
    }
  }
  __syncthreads();
  const int u = tid & 31, ft = (tid >> 5) & 3, cc = tid >> 7;
  ushort_t* op = pvb + ((size_t)jt << 12) + (cc << 11) + (ft << 9);
#pragma unroll
  for (int m = 0; m < 2; ++m) {
    const int l = (u << 1) + m;
    const int f = (ft << 5) + (l & 31);
    const int jb = (cc << 4) + ((l >> 5) << 3);
    ushort4 o0, o1;
    o0.x = s[(jb + 0) * 128 + f]; o0.y = s[(jb + 1) * 128 + f];
    o0.z = s[(jb + 2) * 128 + f]; o0.w = s[(jb + 3) * 128 + f];
    o1.x = s[(jb + 4) * 128 + f]; o1.y = s[(jb + 5) * 128 + f];
    o1.z = s[(jb + 6) * 128 + f]; o1.w = s[(jb + 7) * 128 + f];
    *(ushort4*)(op + (l << 3) + 0) = o0;
    *(ushort4*)(op + (l << 3) + 4) = o1;
  }
}

// ---------------- fused MFMA v11 (r17 best: 52.5us, total 296.9us) --------
// grid (48,8), 24-tile j-strips: 384 blocks @ 2/CU = single dispatch round.
// r19: 3 blocks/CU (768 blocks, slimmed regs) spilled (VGPR 84, WRITE 101MB,
// 79us) — the loop's irreducible live state (qf32+oacc64+a32+s16+temps) can't
// fit the 170-reg budget. 2/CU with VGPR 128 is this decomposition's optimum.
__global__ __launch_bounds__(256, 2) void fused_mfma(
    const ushort_t* __restrict__ obk,  // packed A/Q frags [192][8][64][8]
    const ushort_t* __restrict__ pvb,  // packed PV B frags [192][2][4][64][8]
    const unsigned* __restrict__ bitmap,
    float* __restrict__ neigh,         // 6144x128, pre-zeroed
    float* __restrict__ rowsum,        // 6144, pre-zeroed
    float* __restrict__ scal)          // [S_all, s1, -, sub, ecnt], pre-zeroed
{
  __shared__ float wred[4][4];
  const int tid = threadIdx.x;
  const int w = tid >> 6;
  const int lane = tid & 63;
  const int lo = lane & 31, hi = lane >> 5;
  const int it = (blockIdx.x << 2) + w;  // wave's i-tile (32 rows)
  const int iw = it << 5;
  const int jt0 = blockIdx.y * 24;       // shared j-strip: 24 tiles
  const bool loss_i = (it < 128);        // i < 4096 (wave-uniform)

  bf16x8 qf[8];
  {
    const ushort_t* qp = obk + ((size_t)it << 12) + (lane << 3);
#pragma unroll
    for (int c = 0; c < 8; ++c) qf[c] = *(const bf16x8*)(qp + (c << 9));
  }
  f32x16 oacc[4];
#pragma unroll
  for (int ft = 0; ft < 4; ++ft)
#pragma unroll
    for (int r = 0; r < 16; ++r) oacc[ft][r] = 0.f;
  float rs = 0.f, s_all = 0.f, s1a = 0.f, suba = 0.f, ecf = 0.f;

  bf16x8 a[8];
  {
    const ushort_t* kp = obk + ((size_t)jt0 << 12) + (lane << 3);
#pragma unroll
    for (int c = 0; c < 8; ++c) a[c] = *(const bf16x8*)(kp + (c << 9));
  }

  for (int t = 0; t < 24; ++t) {
    const int jt = jt0 + t;
    f32x16 s0, s1;
#pragma unroll
    for (int r = 0; r < 16; ++r) { s0[r] = 0.f; s1[r] = 0.f; }
    __builtin_amdgcn_s_setprio(1);
#pragma unroll
    for (int c = 0; c < 4; ++c) {
      s0 = __builtin_amdgcn_mfma_f32_32x32x16_bf16(a[c], qf[c], s0, 0, 0, 0);
      s1 = __builtin_amdgcn_mfma_f32_32x32x16_bf16(a[c + 4], qf[c + 4], s1, 0, 0, 0);
    }
    __builtin_amdgcn_s_setprio(0);
    bf16x8 bvf[2][4];
    {
      const ushort_t* vp = pvb + ((size_t)jt << 12) + (lane << 3);
#pragma unroll
      for (int cc = 0; cc < 2; ++cc)
#pragma unroll
        for (int ft = 0; ft < 4; ++ft)
          bvf[cc][ft] = *(const bf16x8*)(vp + (cc << 11) + (ft << 9));
    }
    if (t < 23) {
      const ushort_t* kp = obk + ((size_t)(jt + 1) << 12) + (lane << 3);
#pragma unroll
      for (int c = 0; c < 8; ++c) a[c] = *(const bf16x8*)(kp + (c << 9));
    }
    const bool loss_t = loss_i && (jt < 128);
    unsigned word = 0u;
    if (loss_t) word = bitmap[((unsigned)(iw + lo) << 7) + (unsigned)jt];
    float p[16];
    if (loss_t) {
      ecf += (float)__popc(word & (0x0F0F0F0Fu << (hi << 2)));
#pragma unroll
      for (int r = 0; r < 16; ++r) {
        const float v = s0[r] + s1[r];
        const float sg = __builtin_amdgcn_rcpf(1.f + __expf(-v));
        const int jl = (r & 3) + ((r >> 2) << 3) + (hi << 2);
        const float e_ = (float)((word >> jl) & 1u);
        s_all += sg * sg;
        s1a  += e_ * (sg - 1.f) * (sg - 1.f);
        suba += e_ * sg * sg;
        const float tv = (v >= 0.f) ? sg : 0.f;   // sg>=0.5 <=> v>=0
        p[r] = tv; rs += tv;
      }
    } else {
#pragma unroll
      for (int r = 0; r < 16; ++r) {
        const float v = s0[r] + s1[r];
        const float sg = __builtin_amdgcn_rcpf(1.f + __expf(-v));
        const float tv = (v >= 0.f) ? sg : 0.f;
        p[r] = tv; rs += tv;
      }
    }
#pragma unroll
    for (int cc = 0; cc < 2; ++cc) {
      const int b8 = cc << 3;
      unsigned c01, c23, c45, c67;
      asm("v_cvt_pk_bf16_f32 %0, %1, %2" : "=v"(c01) : "v"(p[b8+0]), "v"(p[b8+1]));
      asm("v_cvt_pk_bf16_f32 %0, %1, %2" : "=v"(c23) : "v"(p[b8+2]), "v"(p[b8+3]));
      asm("v_cvt_pk_bf16_f32 %0, %1, %2" : "=v"(c45) : "v"(p[b8+4]), "v"(p[b8+5]));
      asm("v_cvt_pk_bf16_f32 %0, %1, %2" : "=v"(c67) : "v"(p[b8+6]), "v"(p[b8+7]));
      const auto w0 = __builtin_amdgcn_permlane32_swap((int)c01, (int)c45, false, false);
      const auto w1 = __builtin_amdgcn_permlane32_swap((int)c23, (int)c67, false, false);
      union { int i[4]; bf16x8 h; } u;
      u.i[0] = w0[0]; u.i[1] = w1[0]; u.i[2] = w0[1]; u.i[3] = w1[1];
      __builtin_amdgcn_s_setprio(1);
#pragma unroll
      for (int ft = 0; ft < 4; ++ft)
        oacc[ft] = __builtin_amdgcn_mfma_f32_32x32x16_bf16(u.h, bvf[cc][ft], oacc[ft], 0, 0, 0);
      __builtin_amdgcn_s_setprio(0);
    }
  }
#pragma unroll
  for (int ft = 0; ft < 4; ++ft)
#pragma unroll
    for (int r = 0; r < 16; ++r) {
      const int ir = (r & 3) + ((r >> 2) << 3) + (hi << 2);
      atomicAdd(&neigh[(size_t)(iw + ir) * 128 + (ft << 5) + lo], oacc[ft][r]);
    }
  rs += __shfl_xor(rs, 32, 64);
  if (hi == 0) atomicAdd(&rowsum[iw + lo], rs);
  {
    float v0 = wave_sum(s_all), v1 = wave_sum(s1a), v2 = wave_sum(suba), v3 = wave_sum(ecf);
    if (lane == 0) { wred[w][0] = v0; wred[w][1] = v1; wred[w][2] = v2; wred[w][3] = v3; }
  }
  __syncthreads();
  if (tid < 4) {
    const float t = wred[0][tid] + wred[1][tid] + wred[2][tid] + wred[3][tid];
    const int dst = (tid == 0) ? 0 : (tid == 1) ? 1 : (tid == 2) ? 3 : 4;
    atomicAdd(&scal[dst], t);
  }
}

// ---------------- launcher ----------------
extern "C" void kernel_launch(void* const* d_in, const int* in_sizes, int n_in,
                              void* d_out, int out_size, void* d_ws, size_t ws_size,
                              hipStream_t stream) {
  const float* feat     = (const float*)d_in[0];
  const int*   src      = (const int*)d_in[2];
  const int*   dst      = (const int*)d_in[3];
  const int*   labels   = (const int*)d_in[4];
  const float* W_pool0  = (const float*)d_in[5];
  const float* b_pool0  = (const float*)d_in[6];
  const float* W_self0  = (const float*)d_in[7];
  const float* W_neigh0 = (const float*)d_in[8];
  const float* b0       = (const float*)d_in[9];
  const float* W_pool1  = (const float*)d_in[10];
  const float* b_pool1  = (const float*)d_in[11];
  const float* W_self1  = (const float*)d_in[12];
  const float* W_neigh1 = (const float*)d_in[13];
  const float* b1       = (const float*)d_in[14];
  const float* de_w     = (const float*)d_in[15];
  const float* W_conv   = (const float*)d_in[16];
  const float* W_clf    = (const float*)d_in[17];
  const float* b_clf    = (const float*)d_in[18];
  const float* gaps     = (const float*)d_in[19];
  const int E = in_sizes[2];  // 69632 (E + self-loops)

  float* ws = (float*)d_ws;
  float* p0       = ws + WS_P0;
  float* dots     = ws + WS_DOTS;
  ushort_t* obk   = (ushort_t*)(ws + WS_OBK);
  float* hn0      = ws + WS_HN0;
  unsigned* bitmap= (unsigned*)(ws + WS_BITMAP);
  float* h1       = ws + WS_H1;
  float* h1n      = ws + WS_H1N;
  float* p1       = ws + WS_P1;
  ushort_t* pvb   = (ushort_t*)(ws + WS_PVB);
  float* hn1      = ws + WS_HN1;
  float* h2       = ws + WS_H2;
  float* synth    = ws + WS_X;
  float* neigh    = ws + WS_NEIGH;
  float* rowsum   = ws + WS_ROWSUM;
  float* scal     = ws + WS_SCAL;
  int* deg        = (int*)(ws + WS_DEG);
  int* nn         = (int*)(ws + WS_NN);
  int* cursor     = (int*)(ws + WS_CUR);
  int* rowptr     = (int*)(ws + WS_ROWPTR);
  int* eidx       = (int*)(ws + WS_EIDX);

  float* outp = (float*)d_out;
  const dim3 blk(256);

  // one contiguous zero region: bitmap + neigh + rowsum + scal + deg
  hipMemsetAsync(bitmap, 0, (size_t)(WS_DEG + 4096 - WS_BITMAP) * 4, stream);

  // CSR build + adjacency bitmap
  count_bitmap_k<<<(E + 255) / 256, blk, 0, stream>>>(src, dst, deg, bitmap, E);
  scan_k<<<1, 1024, 0, stream>>>(deg, rowptr, cursor);
  fill_k<<<(E + 255) / 256, blk, 0, stream>>>(src, dst, cursor, eidx, E);

  // layer 0
  mgemm<<<dim3(4, 64), blk, 0, stream>>>(feat, 256, W_pool0, 256,
                                         nullptr, 0, nullptr, 0,
                                         b_pool0, p0, 256, 256, 1, nullptr, nullptr, nullptr,
                                         nullptr, nullptr, nullptr);
  segmax_k<<<4096, 256, 0, stream>>>(p0, rowptr, eidx, hn0, 256);
  mgemm<<<dim3(2, 64), blk, 0, stream>>>(feat, 256, W_self0, 256,
                                         hn0, 256, W_neigh0, 256,
                                         b0, h1, 128, 256, 0, nullptr, nullptr, nullptr,
                                         nullptr, nullptr, nullptr);
  relu_l2norm_k<<<4096, 128, 0, stream>>>(h1, h1n);

  // layer 1
  mgemm<<<dim3(2, 64), blk, 0, stream>>>(h1n, 128, W_pool1, 128,
                                         nullptr, 0, nullptr, 0,
                                         b_pool1, p1, 128, 128, 1, nullptr, nullptr, nullptr,
                                         nullptr, nullptr, nullptr);
  segmax_k<<<4096, 128, 0, stream>>>(p1, rowptr, eidx, hn1, 128);
  mgemm<<<dim3(2, 64), blk, 0, stream>>>(h1n, 128, W_self1, 128,
                                         hn1, 128, W_neigh1, 128,
                                         b1, h2, 128, 128, 0, nullptr, nullptr, nullptr,
                                         nullptr, nullptr, nullptr);

  // SMOTE: dots gemm (diag doubles as sqn), argmin, synth+pvb pack (+y/bias)
  mgemm<<<dim3(16, 16), blk, 0, stream>>>(h2, 128, h2, 128,
                                          nullptr, 0, nullptr, 0,
                                          nullptr, dots, 1024, 128, 0, nullptr, nullptr, nullptr,
                                          nullptr, nullptr, nullptr);
  argmin_k<<<1024, 256, 0, stream>>>(dots, nn);
  build_pack_k<<<192, blk, 0, stream>>>(h2, nn, gaps, synth, pvb, labels, b_clf, outp);

  // decoder gemm writes obk-packed bf16 directly (dots dead -> obk region ok)
  mgemm<<<dim3(2, 96), blk, 0, stream>>>(h2, 128, de_w, 128,
                                         nullptr, 0, nullptr, 0,
                                         nullptr, nullptr, 0, 128, 0, obk, nullptr, synth,
                                         nullptr, nullptr, nullptr);
  // dense fused pass: S_all/s1/sub/ecount + thresholded P@x + rowsum
  fused_mfma<<<dim3(48, 8), blk, 0, stream>>>(obk, pvb, bitmap, neigh, rowsum, scal);

  // classifier: hc never materialized — logits epilogue + loss in the gemm
  mgemm<<<dim3(2, 96), blk, 0, stream>>>(h2, 128, W_conv, 256,
                                         neigh, 128, W_conv + 128, 256,
                                         nullptr, nullptr, 128, 128, 0, nullptr, rowsum, synth,
                                         W_clf, scal, outp);

  (void)n_in; (void)out_size; (void)ws_size; (void)in_sizes;
}